// Round 6
// baseline (288.967 us; speedup 1.0000x reference)
//
#include <hip/hip_runtime.h>
#include <math.h>

#define BB  8
#define SEQ 2048
#define EMB 512
#define NH  8
#define DH  64
#define NBH (BB * NH)                      // 64
#define MROWS (BB * SEQ)                   // 16384
#define QKV_ELEMS ((size_t)NBH * SEQ * DH) // 8388608
#define MASK_ELEMS (BB * (SEQ - 1))        // 16376
// 512^-0.5 * log2(e): q pre-scaled so softmax uses exp2 directly
#define QSCALE 0.06375871307545f

typedef __attribute__((ext_vector_type(8))) short short8;
typedef __attribute__((ext_vector_type(4))) float float4e;
typedef unsigned short ushort_t;

static __device__ inline unsigned short f2bf(float f) {
    unsigned int u = __float_as_uint(f);
    unsigned int r = (u + 0x7fffu + ((u >> 16) & 1u)) >> 16;
    return (unsigned short)r;
}

static __device__ inline float bf2f(unsigned short h) {
    return __uint_as_float((unsigned int)h << 16);
}

// truncating pack of two f32 -> two bf16 in one u32 (lo=a, hi=b)
static __device__ inline unsigned int pk_bf_trunc(float a, float b) {
    return (__float_as_uint(a) >> 16) | (__float_as_uint(b) & 0xffff0000u);
}

static __device__ inline void gl_lds16(const unsigned short* g, unsigned short* l) {
    __builtin_amdgcn_global_load_lds(
        (const __attribute__((address_space(1))) void*)g,
        (__attribute__((address_space(3))) void*)l, 16, 0, 0);
}

// ---------------------------------------------------------------------------
// Mask decode -> bf16 per-token mask pmh[B][SEQ] (1.0/0.0; CLS=1 at n==0).
// 64 blocks; each block full-scans the word array for layout detect (L2-hot),
// then decodes its 256-element slice.
// ---------------------------------------------------------------------------
__global__ __launch_bounds__(256) void decode_mask(const void* __restrict__ mraw,
                                                   ushort_t* __restrict__ pmh) {
    __shared__ int flag;
    if (threadIdx.x == 0) flag = 0;
    __syncthreads();
    const unsigned int* mi = (const unsigned int*)mraw;
    int local = 0;
    for (int i = threadIdx.x; i < MASK_ELEMS / 4; i += 256) {
        if (mi[i] > 1u) local = 1;
    }
    if (local) flag = 1;
    __syncthreads();
    const int isbyte = flag;
    const unsigned char* mb = (const unsigned char*)mraw;
    const int* m32 = (const int*)mraw;
    const int i = blockIdx.x * 256 + threadIdx.x;
    const int b = i >> 11, n = i & (SEQ - 1);
    int v;
    if (n == 0) v = 1;
    else {
        const int src = b * (SEQ - 1) + n - 1;
        v = isbyte ? (int)mb[src] : (m32[src] != 0 ? 1 : 0);
    }
    pmh[i] = v ? 0x3F80 : 0;
}

// ---------------------------------------------------------------------------
// x fp32 -> bf16.
// ---------------------------------------------------------------------------
__global__ __launch_bounds__(256) void conv_x(const float* __restrict__ x,
                                              ushort_t* __restrict__ xb) {
    const size_t i = ((size_t)blockIdx.x * 256 + threadIdx.x) * 4;
    float4 v = *(const float4*)&x[i];
    ushort4 o;
    o.x = f2bf(v.x); o.y = f2bf(v.y); o.z = f2bf(v.z); o.w = f2bf(v.w);
    *(ushort4*)&xb[i] = o;
}

// ---------------------------------------------------------------------------
// Weight transpose: src fp32 [K][N] -> dst bf16 [N][K].
// ---------------------------------------------------------------------------
__global__ __launch_bounds__(256) void wtrans(const float* __restrict__ src,
                                              ushort_t* __restrict__ dst,
                                              int K, int N) {
    __shared__ float T[32][33];
    const int tid = threadIdx.x;
    const int n0 = blockIdx.x * 32;
    const int k0 = blockIdx.y * 32;
    {
        const int r = tid >> 3, c4 = (tid & 7) * 4;
        *(float4*)&T[r][c4] = *(const float4*)&src[(size_t)(k0 + r) * N + n0 + c4];
    }
    __syncthreads();
    const int n = tid >> 3, k4 = (tid & 7) * 4;
    ushort4 hv;
    hv.x = f2bf(T[k4 + 0][n]);
    hv.y = f2bf(T[k4 + 1][n]);
    hv.z = f2bf(T[k4 + 2][n]);
    hv.w = f2bf(T[k4 + 3][n]);
    *(ushort4*)&dst[(size_t)(n0 + n) * K + k0 + k4] = hv;
}

// ---------------------------------------------------------------------------
// MFMA GEMM 1: qkv = xb @ WqkvT + bqkv.
//   q -> qb [BH][N][DH] (pre-scaled by QSCALE), k -> kb, v -> vt [BH][DH][N].
// ---------------------------------------------------------------------------
__global__ __launch_bounds__(256) void qkv_mfma(const ushort_t* __restrict__ xb,
                                                const ushort_t* __restrict__ wt,
                                                const float* __restrict__ bias,
                                                ushort_t* __restrict__ qb,
                                                ushort_t* __restrict__ kb,
                                                ushort_t* __restrict__ vt) {
    __shared__ __align__(16) ushort_t As[128 * 32];
    __shared__ __align__(16) ushort_t Bs[128 * 32];
    const int tid  = threadIdx.x;
    const int w    = tid >> 6;
    const int lane = tid & 63;
    const int l16  = lane & 15;
    const int quad = lane >> 4;
    const int wq   = w >> 1;
    const int wn   = w & 1;
    const int row0 = blockIdx.y * 128;
    const int col0 = blockIdx.x * 128;

    float4e acc[4][4];
    #pragma unroll
    for (int i = 0; i < 4; ++i)
        #pragma unroll
        for (int j = 0; j < 4; ++j) acc[i][j] = (float4e){0.f, 0.f, 0.f, 0.f};

    const int srow = tid >> 2;
    const int csrc = (tid & 3) ^ (srow & 3);

    for (int k0 = 0; k0 < EMB; k0 += 32) {
        #pragma unroll
        for (int s = 0; s < 2; ++s) {
            const int row = s * 64 + srow;
            gl_lds16(xb + (size_t)(row0 + row) * EMB + k0 + csrc * 8,
                     As + s * 2048 + w * 512);
            gl_lds16(wt + (size_t)(col0 + row) * EMB + k0 + csrc * 8,
                     Bs + s * 2048 + w * 512);
        }
        __syncthreads();
        short8 af[4], bf[4];
        #pragma unroll
        for (int mt = 0; mt < 4; ++mt) {
            const int rm = wq * 64 + mt * 16 + l16;
            af[mt] = *(const short8*)(As + rm * 32 + ((quad ^ (rm & 3)) * 8));
        }
        #pragma unroll
        for (int nt = 0; nt < 4; ++nt) {
            const int rn = wn * 64 + nt * 16 + l16;
            bf[nt] = *(const short8*)(Bs + rn * 32 + ((quad ^ (rn & 3)) * 8));
        }
        #pragma unroll
        for (int mt = 0; mt < 4; ++mt)
            #pragma unroll
            for (int nt = 0; nt < 4; ++nt)
                acc[mt][nt] = __builtin_amdgcn_mfma_f32_16x16x32_bf16(af[mt], bf[nt], acc[mt][nt], 0, 0, 0);
        __syncthreads();
    }

    #pragma unroll
    for (int nt = 0; nt < 4; ++nt) {
        const int cb    = col0 + wn * 64 + nt * 16;
        const int which = cb >> 9;
        const int h     = (cb >> 6) & 7;
        const int dcol  = (cb & 63) + l16;
        const float bz  = bias[cb + l16];
        if (which == 2) {
            #pragma unroll
            for (int mt = 0; mt < 4; ++mt) {
                const int rg = row0 + wq * 64 + mt * 16 + quad * 4;
                const int b = rg >> 11, n = rg & (SEQ - 1);
                ushort4 ov;
                ov.x = f2bf(acc[mt][nt][0] + bz);
                ov.y = f2bf(acc[mt][nt][1] + bz);
                ov.z = f2bf(acc[mt][nt][2] + bz);
                ov.w = f2bf(acc[mt][nt][3] + bz);
                *(ushort4*)&vt[((size_t)(b * NH + h) * DH + dcol) * SEQ + n] = ov;
            }
        } else {
            ushort_t* base = (which == 0) ? qb : kb;
            const float sc = (which == 0) ? QSCALE : 1.0f;
            #pragma unroll
            for (int mt = 0; mt < 4; ++mt) {
                #pragma unroll
                for (int i = 0; i < 4; ++i) {
                    const int rg = row0 + wq * 64 + mt * 16 + quad * 4 + i;
                    const int b = rg >> 11;
                    const int n = rg & (SEQ - 1);
                    base[((size_t)(b * NH + h) * SEQ + n) * DH + dcol] =
                        f2bf((acc[mt][nt][i] + bz) * sc);
                }
            }
        }
    }
}

// ---------------------------------------------------------------------------
// MFMA flash attention v4: BARRIER-FREE K-loop.
// K and V fragments are loaded straight from global in MFMA operand layout
// (kb [bh][key][dh] rows for the A-operand of S^T; vt [bh][dh][key] rows for
// the B-operand of PV) — no shared-tile staging, no __syncthreads in the loop.
// Each wave owns 64 q rows (4 groups of 16) and streams all 2048 keys.
// P round-trips through a per-wave LDS buffer (XOR-swizzled, b64 writes /
// b128 reads), ordered by compiler lgkmcnt only.
// Fixed-max softmax: p = mq ? exp2(s)*mk : 1  (exact reference semantics;
// masked-q rows get uniform 1/2048 -> mean(V)).
// ---------------------------------------------------------------------------
__global__ __launch_bounds__(256, 2) void attn_mfma(const ushort_t* __restrict__ qb,
                                                    const ushort_t* __restrict__ kb,
                                                    const ushort_t* __restrict__ vt,
                                                    const ushort_t* __restrict__ pmh,
                                                    ushort_t* __restrict__ ab) {
    __shared__ __align__(16) ushort_t Ps[4][64 * 64]; // 8KB per wave
    __shared__ ushort_t mskh[SEQ];                    // 4KB
    __shared__ float lw[4][64];

    const int tid  = threadIdx.x;
    const int qt   = blockIdx.x & 7;     // 8 tiles of 256 q rows
    const int bh   = blockIdx.x >> 3;
    const int b    = bh >> 3;
    const int h    = bh & 7;
    const int w    = tid >> 6;
    const int lane = tid & 63;
    const int l16  = lane & 15;
    const int quad = lane >> 4;

    // stage bf16 mask row for this batch
    *(short8*)(mskh + tid * 8) = *(const short8*)(pmh + b * SEQ + tid * 8);

    const int q0 = qt * 256 + w * 64;    // wave's first q row

    // Q fragments (B-operand): lane n=l16 -> q, k=quad*8+j -> dh
    const ushort_t* qbase = qb + ((size_t)bh * SEQ + q0 + l16) * DH;
    short8 qf0[4], qf1[4];
    #pragma unroll
    for (int g = 0; g < 4; ++g) {
        qf0[g] = *(const short8*)(qbase + g * 16 * DH + quad * 8);
        qf1[g] = *(const short8*)(qbase + g * 16 * DH + 32 + quad * 8);
    }

    __syncthreads();  // mask ready (only barrier before epilogue)

    bool bq[4];
    #pragma unroll
    for (int g = 0; g < 4; ++g)
        bq[g] = bf2f(mskh[q0 + g * 16 + l16]) > 0.5f;

    float4e o[4][4];
    #pragma unroll
    for (int g = 0; g < 4; ++g)
        #pragma unroll
        for (int d = 0; d < 4; ++d) o[g][d] = (float4e){0.f, 0.f, 0.f, 0.f};
    float l_i[4] = {0.f, 0.f, 0.f, 0.f};

    const ushort_t* kbh = kb + (size_t)bh * SEQ * DH;
    const ushort_t* vbh = vt + (size_t)bh * DH * SEQ;

    // P LDS addressing (bytes), swizzle h = l16&7 (row q = g*16+l16)
    char* Pw = (char*)&Ps[w][0];
    const int hsw = l16 & 7;
    int pcB[4], prB[2];
    #pragma unroll
    for (int bkb = 0; bkb < 4; ++bkb)
        pcB[bkb] = (((2 * bkb + (quad >> 1)) ^ hsw) * 16) + ((quad & 1) * 8);
    #pragma unroll
    for (int kc = 0; kc < 2; ++kc)
        prB[kc] = ((kc * 4 + quad) ^ hsw) * 16;

    for (int kt = 0; kt < 32; ++kt) {
        const ushort_t* kB = kbh + (size_t)kt * 64 * DH;
        const ushort_t* vB = vbh + kt * 64;

        // ---- S^T blocks: A = K (from global), B = Q (regs) ----
        #pragma unroll
        for (int bkb = 0; bkb < 4; ++bkb) {
            const ushort_t* krow = kB + (size_t)(bkb * 16 + l16) * DH + quad * 8;
            const short8 kf0 = *(const short8*)(krow);
            const short8 kf1 = *(const short8*)(krow + 32);
            float4e st[4];
            #pragma unroll
            for (int g = 0; g < 4; ++g) {
                st[g] = (float4e){0.f, 0.f, 0.f, 0.f};
                st[g] = __builtin_amdgcn_mfma_f32_16x16x32_bf16(kf0, qf0[g], st[g], 0, 0, 0);
                st[g] = __builtin_amdgcn_mfma_f32_16x16x32_bf16(kf1, qf1[g], st[g], 0, 0, 0);
            }
            // key masks for keys bkb*16 + quad*4 + i (broadcast per quad)
            const ushort4 mk4 = *(const ushort4*)(mskh + kt * 64 + bkb * 16 + quad * 4);
            const float mkf[4] = {bf2f(mk4.x), bf2f(mk4.y), bf2f(mk4.z), bf2f(mk4.w)};
            #pragma unroll
            for (int g = 0; g < 4; ++g) {
                const float p0 = bq[g] ? __builtin_amdgcn_exp2f(st[g][0]) * mkf[0] : 1.0f;
                const float p1 = bq[g] ? __builtin_amdgcn_exp2f(st[g][1]) * mkf[1] : 1.0f;
                const float p2 = bq[g] ? __builtin_amdgcn_exp2f(st[g][2]) * mkf[2] : 1.0f;
                const float p3 = bq[g] ? __builtin_amdgcn_exp2f(st[g][3]) * mkf[3] : 1.0f;
                l_i[g] += (p0 + p1) + (p2 + p3);
                uint2 pk;
                pk.x = pk_bf_trunc(p0, p1);
                pk.y = pk_bf_trunc(p2, p3);
                *(uint2*)(Pw + (g * 16 + l16) * 128 + pcB[bkb]) = pk;
            }
        }

        // ---- PV: A = P (LDS), B = V (from global) ----
        short8 pf[4][2];
        #pragma unroll
        for (int g = 0; g < 4; ++g)
            #pragma unroll
            for (int kc = 0; kc < 2; ++kc)
                pf[g][kc] = *(const short8*)(Pw + (g * 16 + l16) * 128 + prB[kc]);
        #pragma unroll
        for (int dhb = 0; dhb < 4; ++dhb) {
            const ushort_t* vrow = vB + (size_t)(dhb * 16 + l16) * SEQ + quad * 8;
            #pragma unroll
            for (int kc = 0; kc < 2; ++kc) {
                const short8 vf = *(const short8*)(vrow + kc * 32);
                #pragma unroll
                for (int g = 0; g < 4; ++g)
                    o[g][dhb] = __builtin_amdgcn_mfma_f32_16x16x32_bf16(pf[g][kc], vf, o[g][dhb], 0, 0, 0);
            }
        }
    }

    // l: per-lane partial covers 16 keys; sum across quads (lanes xor 16,32)
    #pragma unroll
    for (int g = 0; g < 4; ++g) {
        float l = l_i[g];
        l += __shfl_xor(l, 16);
        l += __shfl_xor(l, 32);
        lw[w][g * 16 + l16] = l;  // all quads write same value
    }

    ushort_t* ob = ab + ((size_t)b * SEQ + q0) * EMB + h * DH;
    #pragma unroll
    for (int g = 0; g < 4; ++g) {
        #pragma unroll
        for (int i = 0; i < 4; ++i) {
            const int row = g * 16 + quad * 4 + i;
            const float inv = 1.0f / lw[w][row];
            #pragma unroll
            for (int dhb = 0; dhb < 4; ++dhb)
                ob[(size_t)row * EMB + dhb * 16 + l16] = f2bf(o[g][dhb][i] * inv);
        }
    }
}

// ---------------------------------------------------------------------------
// MFMA GEMM 2: out = ab @ WoutT + bout (fp32 out).
// ---------------------------------------------------------------------------
__global__ __launch_bounds__(256) void out_mfma(const ushort_t* __restrict__ ab,
                                                const ushort_t* __restrict__ wot,
                                                const float* __restrict__ bias,
                                                float* __restrict__ out) {
    __shared__ __align__(16) ushort_t As[128 * 32];
    __shared__ __align__(16) ushort_t Bs[128 * 32];
    const int tid  = threadIdx.x;
    const int w    = tid >> 6;
    const int lane = tid & 63;
    const int l16  = lane & 15;
    const int quad = lane >> 4;
    const int wq   = w >> 1;
    const int wn   = w & 1;
    const int row0 = blockIdx.y * 128;
    const int col0 = blockIdx.x * 128;

    float4e acc[4][4];
    #pragma unroll
    for (int i = 0; i < 4; ++i)
        #pragma unroll
        for (int j = 0; j < 4; ++j) acc[i][j] = (float4e){0.f, 0.f, 0.f, 0.f};

    const int srow = tid >> 2;
    const int csrc = (tid & 3) ^ (srow & 3);

    for (int k0 = 0; k0 < EMB; k0 += 32) {
        #pragma unroll
        for (int s = 0; s < 2; ++s) {
            const int row = s * 64 + srow;
            gl_lds16(ab + (size_t)(row0 + row) * EMB + k0 + csrc * 8,
                     As + s * 2048 + w * 512);
            gl_lds16(wot + (size_t)(col0 + row) * EMB + k0 + csrc * 8,
                     Bs + s * 2048 + w * 512);
        }
        __syncthreads();
        short8 af[4], bf[4];
        #pragma unroll
        for (int mt = 0; mt < 4; ++mt) {
            const int rm = wq * 64 + mt * 16 + l16;
            af[mt] = *(const short8*)(As + rm * 32 + ((quad ^ (rm & 3)) * 8));
        }
        #pragma unroll
        for (int nt = 0; nt < 4; ++nt) {
            const int rn = wn * 64 + nt * 16 + l16;
            bf[nt] = *(const short8*)(Bs + rn * 32 + ((quad ^ (rn & 3)) * 8));
        }
        #pragma unroll
        for (int mt = 0; mt < 4; ++mt)
            #pragma unroll
            for (int nt = 0; nt < 4; ++nt)
                acc[mt][nt] = __builtin_amdgcn_mfma_f32_16x16x32_bf16(af[mt], bf[nt], acc[mt][nt], 0, 0, 0);
        __syncthreads();
    }

    #pragma unroll
    for (int nt = 0; nt < 4; ++nt) {
        const int col_g = col0 + wn * 64 + nt * 16 + l16;
        const float bz = bias[col_g];
        #pragma unroll
        for (int mt = 0; mt < 4; ++mt) {
            #pragma unroll
            for (int i = 0; i < 4; ++i) {
                const int row_g = row0 + wq * 64 + mt * 16 + quad * 4 + i;
                out[(size_t)row_g * EMB + col_g] = acc[mt][nt][i] + bz;
            }
        }
    }
}

// ---------------------------------------------------------------------------
extern "C" void kernel_launch(void* const* d_in, const int* in_sizes, int n_in,
                              void* d_out, int out_size, void* d_ws, size_t ws_size,
                              hipStream_t stream) {
    const float* x    = (const float*)d_in[0];
    const void*  mask = d_in[1];
    const float* Wqkv = (const float*)d_in[2];
    const float* bqkv = (const float*)d_in[3];
    const float* Wout = (const float*)d_in[4];
    const float* bout = (const float*)d_in[5];
    float* out = (float*)d_out;

    ushort_t* xb  = (ushort_t*)d_ws;                 // [16384][512]
    ushort_t* wqt = xb + (size_t)MROWS * EMB;        // [1536][512]
    ushort_t* wot = wqt + (size_t)1536 * EMB;        // [512][512]
    ushort_t* qb  = wot + (size_t)EMB * EMB;         // [BH][N][DH]
    ushort_t* kb  = qb + QKV_ELEMS;
    ushort_t* vt  = kb + QKV_ELEMS;                  // [BH][DH][N]
    ushort_t* ab  = vt + QKV_ELEMS;                  // [B][N][EMB]
    ushort_t* pmh = ab + (size_t)MROWS * EMB;        // bf16 [B][SEQ]

    decode_mask<<<dim3(64), 256, 0, stream>>>(mask, pmh);
    conv_x<<<dim3(MROWS * EMB / 1024), 256, 0, stream>>>(x, xb);
    wtrans<<<dim3(1536 / 32, EMB / 32), 256, 0, stream>>>(Wqkv, wqt, EMB, 1536);
    wtrans<<<dim3(EMB / 32, EMB / 32), 256, 0, stream>>>(Wout, wot, EMB, EMB);
    qkv_mfma<<<dim3(1536 / 128, MROWS / 128), 256, 0, stream>>>(xb, wqt, bqkv, qb, kb, vt);
    attn_mfma<<<dim3(NBH * (SEQ / 256)), 256, 0, stream>>>(qb, kb, vt, pmh, ab);
    out_mfma<<<dim3(EMB / 128, MROWS / 128), 256, 0, stream>>>(ab, wot, bout, out);
}

// Round 7
// 280.016 us; speedup vs baseline: 1.0320x; 1.0320x over previous
//
#include <hip/hip_runtime.h>
#include <math.h>

#define BB  8
#define SEQ 2048
#define EMB 512
#define NH  8
#define DH  64
#define NBH (BB * NH)                      // 64
#define MROWS (BB * SEQ)                   // 16384
#define QKV_ELEMS ((size_t)NBH * SEQ * DH) // 8388608
#define MASK_ELEMS (BB * (SEQ - 1))        // 16376
// 512^-0.5 * log2(e): q pre-scaled so softmax uses exp2 directly
#define QSCALE 0.06375871307545f

typedef __attribute__((ext_vector_type(8))) short short8;
typedef __attribute__((ext_vector_type(4))) float float4e;
typedef unsigned short ushort_t;

static __device__ inline unsigned short f2bf(float f) {
    unsigned int u = __float_as_uint(f);
    unsigned int r = (u + 0x7fffu + ((u >> 16) & 1u)) >> 16;
    return (unsigned short)r;
}

static __device__ inline float bf2f(unsigned short h) {
    return __uint_as_float((unsigned int)h << 16);
}

static __device__ inline void gl_lds16(const unsigned short* g, unsigned short* l) {
    __builtin_amdgcn_global_load_lds(
        (const __attribute__((address_space(1))) void*)g,
        (__attribute__((address_space(3))) void*)l, 16, 0, 0);
}

// ---------------------------------------------------------------------------
// Fused prep: one launch, blockIdx-partitioned.
//   [0, 8192)        conv_x : x fp32 -> xb bf16
//   [8192, 8256)     decode_mask -> pmh bf16 [B][SEQ]
//   [8256, 9024)     wtrans Wqkv fp32 [512][1536] -> wqt bf16 [1536][512]
//   [9024, 9280)     wtrans Wout fp32 [512][512]  -> wot bf16 [512][512]
// ---------------------------------------------------------------------------
#define PREP_CONV   8192
#define PREP_MASK   (PREP_CONV + 64)
#define PREP_WQ     (PREP_MASK + (1536 / 32) * (EMB / 32))
#define PREP_TOTAL  (PREP_WQ + (EMB / 32) * (EMB / 32))

__global__ __launch_bounds__(256) void prep(const float* __restrict__ x,
                                            const void* __restrict__ mraw,
                                            const float* __restrict__ Wqkv,
                                            const float* __restrict__ Wout,
                                            ushort_t* __restrict__ xb,
                                            ushort_t* __restrict__ pmh,
                                            ushort_t* __restrict__ wqt,
                                            ushort_t* __restrict__ wot) {
    __shared__ float T[32][33];
    __shared__ int flag;
    const int bid = blockIdx.x;
    const int tid = threadIdx.x;

    if (bid < PREP_CONV) {
        const size_t i = ((size_t)bid * 256 + tid) * 4;
        float4 v = *(const float4*)&x[i];
        ushort4 o;
        o.x = f2bf(v.x); o.y = f2bf(v.y); o.z = f2bf(v.z); o.w = f2bf(v.w);
        *(ushort4*)&xb[i] = o;
    } else if (bid < PREP_MASK) {
        if (tid == 0) flag = 0;
        __syncthreads();
        const unsigned int* mi = (const unsigned int*)mraw;
        int local = 0;
        for (int i = tid; i < MASK_ELEMS / 4; i += 256) {
            if (mi[i] > 1u) local = 1;
        }
        if (local) flag = 1;
        __syncthreads();
        const int isbyte = flag;
        const unsigned char* mb = (const unsigned char*)mraw;
        const int* m32 = (const int*)mraw;
        const int i = (bid - PREP_CONV) * 256 + tid;
        const int b = i >> 11, n = i & (SEQ - 1);
        int v;
        if (n == 0) v = 1;
        else {
            const int src = b * (SEQ - 1) + n - 1;
            v = isbyte ? (int)mb[src] : (m32[src] != 0 ? 1 : 0);
        }
        pmh[i] = v ? 0x3F80 : 0;
    } else {
        const float* src;
        ushort_t* dst;
        int N, idx;
        if (bid < PREP_WQ) {
            src = Wqkv; dst = wqt; N = 1536; idx = bid - PREP_MASK;
        } else {
            src = Wout; dst = wot; N = EMB; idx = bid - PREP_WQ;
        }
        const int nb = N / 32;
        const int n0 = (idx % nb) * 32;
        const int k0 = (idx / nb) * 32;
        {
            const int r = tid >> 3, c4 = (tid & 7) * 4;
            *(float4*)&T[r][c4] = *(const float4*)&src[(size_t)(k0 + r) * N + n0 + c4];
        }
        __syncthreads();
        const int n = tid >> 3, k4 = (tid & 7) * 4;
        ushort4 hv;
        hv.x = f2bf(T[k4 + 0][n]);
        hv.y = f2bf(T[k4 + 1][n]);
        hv.z = f2bf(T[k4 + 2][n]);
        hv.w = f2bf(T[k4 + 3][n]);
        *(ushort4*)&dst[(size_t)(n0 + n) * EMB + k0 + k4] = hv;
    }
}

// ---------------------------------------------------------------------------
// MFMA GEMM 1: qkv = xb @ WqkvT + bqkv.
//   q -> qb [BH][N][DH] (pre-scaled by QSCALE), k -> kb, v -> vt [BH][DH][N].
// ---------------------------------------------------------------------------
__global__ __launch_bounds__(256) void qkv_mfma(const ushort_t* __restrict__ xb,
                                                const ushort_t* __restrict__ wt,
                                                const float* __restrict__ bias,
                                                ushort_t* __restrict__ qb,
                                                ushort_t* __restrict__ kb,
                                                ushort_t* __restrict__ vt) {
    __shared__ __align__(16) ushort_t As[128 * 32];
    __shared__ __align__(16) ushort_t Bs[128 * 32];
    const int tid  = threadIdx.x;
    const int w    = tid >> 6;
    const int lane = tid & 63;
    const int l16  = lane & 15;
    const int quad = lane >> 4;
    const int wq   = w >> 1;
    const int wn   = w & 1;
    const int row0 = blockIdx.y * 128;
    const int col0 = blockIdx.x * 128;

    float4e acc[4][4];
    #pragma unroll
    for (int i = 0; i < 4; ++i)
        #pragma unroll
        for (int j = 0; j < 4; ++j) acc[i][j] = (float4e){0.f, 0.f, 0.f, 0.f};

    const int srow = tid >> 2;
    const int csrc = (tid & 3) ^ (srow & 3);

    for (int k0 = 0; k0 < EMB; k0 += 32) {
        #pragma unroll
        for (int s = 0; s < 2; ++s) {
            const int row = s * 64 + srow;
            gl_lds16(xb + (size_t)(row0 + row) * EMB + k0 + csrc * 8,
                     As + s * 2048 + w * 512);
            gl_lds16(wt + (size_t)(col0 + row) * EMB + k0 + csrc * 8,
                     Bs + s * 2048 + w * 512);
        }
        __syncthreads();
        short8 af[4], bf[4];
        #pragma unroll
        for (int mt = 0; mt < 4; ++mt) {
            const int rm = wq * 64 + mt * 16 + l16;
            af[mt] = *(const short8*)(As + rm * 32 + ((quad ^ (rm & 3)) * 8));
        }
        #pragma unroll
        for (int nt = 0; nt < 4; ++nt) {
            const int rn = wn * 64 + nt * 16 + l16;
            bf[nt] = *(const short8*)(Bs + rn * 32 + ((quad ^ (rn & 3)) * 8));
        }
        #pragma unroll
        for (int mt = 0; mt < 4; ++mt)
            #pragma unroll
            for (int nt = 0; nt < 4; ++nt)
                acc[mt][nt] = __builtin_amdgcn_mfma_f32_16x16x32_bf16(af[mt], bf[nt], acc[mt][nt], 0, 0, 0);
        __syncthreads();
    }

    #pragma unroll
    for (int nt = 0; nt < 4; ++nt) {
        const int cb    = col0 + wn * 64 + nt * 16;
        const int which = cb >> 9;
        const int h     = (cb >> 6) & 7;
        const int dcol  = (cb & 63) + l16;
        const float bz  = bias[cb + l16];
        if (which == 2) {
            #pragma unroll
            for (int mt = 0; mt < 4; ++mt) {
                const int rg = row0 + wq * 64 + mt * 16 + quad * 4;
                const int b = rg >> 11, n = rg & (SEQ - 1);
                ushort4 ov;
                ov.x = f2bf(acc[mt][nt][0] + bz);
                ov.y = f2bf(acc[mt][nt][1] + bz);
                ov.z = f2bf(acc[mt][nt][2] + bz);
                ov.w = f2bf(acc[mt][nt][3] + bz);
                *(ushort4*)&vt[((size_t)(b * NH + h) * DH + dcol) * SEQ + n] = ov;
            }
        } else {
            ushort_t* base = (which == 0) ? qb : kb;
            const float sc = (which == 0) ? QSCALE : 1.0f;
            #pragma unroll
            for (int mt = 0; mt < 4; ++mt) {
                #pragma unroll
                for (int i = 0; i < 4; ++i) {
                    const int rg = row0 + wq * 64 + mt * 16 + quad * 4 + i;
                    const int b = rg >> 11;
                    const int n = rg & (SEQ - 1);
                    base[((size_t)(b * NH + h) * SEQ + n) * DH + dcol] =
                        f2bf((acc[mt][nt][i] + bz) * sc);
                }
            }
        }
    }
}

// ---------------------------------------------------------------------------
// MFMA flash attention v5 = round-5 structure + VGPR-prefetch staging.
// Per kt: [barrier] ds_write K/V regs (loaded during previous compute)
// [barrier] issue global loads for kt+1 -> regs, compute kt. The prefetch
// loads have the entire compute phase in flight before the next barrier's
// vmcnt drain touches them -> memory latency hidden at 4 blocks/CU.
// Wave owns 32 q rows; S computed transposed (A=K, B=Q); fixed-max softmax.
// ---------------------------------------------------------------------------
__global__ __launch_bounds__(256, 4) void attn_mfma(const ushort_t* __restrict__ qb,
                                                    const ushort_t* __restrict__ kb,
                                                    const ushort_t* __restrict__ vt,
                                                    const ushort_t* __restrict__ pmh,
                                                    ushort_t* __restrict__ ab) {
    __shared__ __align__(16) ushort_t Ks[64 * 64];     // 8KB  [key][dh]
    __shared__ __align__(16) ushort_t Vts[64 * 64];    // 8KB  [dh][key]
    __shared__ __align__(16) ushort_t Ps[4][32 * 64];  // 16KB [wave][q][key]
    __shared__ ushort_t mskh[SEQ];                     // 4KB
    __shared__ float lw[128];

    const int tid  = threadIdx.x;
    const int qt   = blockIdx.x & 15;     // 128-row q tile
    const int bh   = blockIdx.x >> 4;
    const int b    = bh >> 3;
    const int h    = bh & 7;
    const int w    = tid >> 6;
    const int lane = tid & 63;
    const int l16  = lane & 15;
    const int quad = lane >> 4;

    // stage bf16 mask row for this batch (visible after first loop barrier)
    *(short8*)(mskh + tid * 8) = *(const short8*)(pmh + b * SEQ + tid * 8);

    // Q fragments for 2 groups of 16 rows: q row = qt*128 + w*32 + g*16 + l16
    const ushort_t* qbase = qb + ((size_t)bh * SEQ + qt * 128 + w * 32 + l16) * DH;
    short8 qf0[2], qf1[2];
    #pragma unroll
    for (int g = 0; g < 2; ++g) {
        qf0[g] = *(const short8*)(qbase + g * 16 * DH + quad * 8);
        qf1[g] = *(const short8*)(qbase + g * 16 * DH + 32 + quad * 8);
    }

    // q masks straight from global (L2-hot; values identical to mskh)
    float mqf[2], fnq[2];
    #pragma unroll
    for (int g = 0; g < 2; ++g) {
        mqf[g] = bf2f(pmh[b * SEQ + qt * 128 + w * 32 + g * 16 + l16]);
        fnq[g] = 1.0f - mqf[g];
    }

    float4e o[2][4];
    #pragma unroll
    for (int g = 0; g < 2; ++g)
        #pragma unroll
        for (int d = 0; d < 4; ++d) o[g][d] = (float4e){0.f, 0.f, 0.f, 0.f};
    float l_i[2] = {0.f, 0.f};

    // staging chunk assignment: chunk c = s*256 + tid, tile row = c>>3,
    // global col = (c&7)*8, LDS dest swizzled ((c&7)^(row&7))*8
    int crow[2], ccol[2], cdst[2];
    #pragma unroll
    for (int s = 0; s < 2; ++s) {
        const int c = s * 256 + tid;
        crow[s] = c >> 3;
        ccol[s] = (c & 7) * 8;
        cdst[s] = crow[s] * 64 + (((c & 7) ^ (crow[s] & 7)) * 8);
    }
    const ushort_t* kptr = kb + (size_t)bh * SEQ * DH;
    const ushort_t* vptr = vt + (size_t)bh * DH * SEQ;

    // K/V fragment LDS offsets (kt-invariant)
    int koff0[4], koff1[4];
    #pragma unroll
    for (int t = 0; t < 4; ++t) {
        const int row = t * 16 + l16;
        koff0[t] = row * 64 + ((quad ^ (row & 7)) * 8);
        koff1[t] = row * 64 + (((4 + quad) ^ (row & 7)) * 8);
    }
    // P LDS addressing (ushort units), swizzle psw = 2*(l16&7) (even XOR
    // keeps the b128 read pairs adjacent)
    const int psw = (l16 & 7) * 2;
    ushort_t* pwv = &Ps[w][0];
    const int prd0 = ((quad * 2) ^ psw) * 4;
    const int prd1 = (((4 + quad) * 2) ^ psw) * 4;

    // prologue: load kt=0 staging chunks into regs
    short8 kreg[2], vreg[2];
    #pragma unroll
    for (int s = 0; s < 2; ++s) {
        kreg[s] = *(const short8*)(kptr + (size_t)crow[s] * DH + ccol[s]);
        vreg[s] = *(const short8*)(vptr + (size_t)crow[s] * SEQ + ccol[s]);
    }

    for (int kt = 0; kt < 32; ++kt) {
        __syncthreads();  // all waves done reading previous tile
        #pragma unroll
        for (int s = 0; s < 2; ++s) {
            *(short8*)(Ks + cdst[s])  = kreg[s];
            *(short8*)(Vts + cdst[s]) = vreg[s];
        }
        __syncthreads();  // tile (and, at kt=0, mask) visible

        // prefetch kt+1 into regs; in flight across the whole compute phase
        if (kt < 31) {
            #pragma unroll
            for (int s = 0; s < 2; ++s) {
                kreg[s] = *(const short8*)(kptr + (size_t)((kt + 1) * 64 + crow[s]) * DH + ccol[s]);
                vreg[s] = *(const short8*)(vptr + (size_t)crow[s] * SEQ + (kt + 1) * 64 + ccol[s]);
            }
        }

        // ---- S^T = K·Q^T per 16-key block; exp+mask+pack immediately ----
        #pragma unroll
        for (int bkb = 0; bkb < 4; ++bkb) {
            const short8 kf0 = *(const short8*)(Ks + koff0[bkb]);
            const short8 kf1 = *(const short8*)(Ks + koff1[bkb]);
            float4e st[2];
            #pragma unroll
            for (int g = 0; g < 2; ++g) {
                st[g] = (float4e){0.f, 0.f, 0.f, 0.f};
                st[g] = __builtin_amdgcn_mfma_f32_16x16x32_bf16(kf0, qf0[g], st[g], 0, 0, 0);
                st[g] = __builtin_amdgcn_mfma_f32_16x16x32_bf16(kf1, qf1[g], st[g], 0, 0, 0);
            }
            // key masks for keys bkb*16 + quad*4 + i
            const ushort4 mk4 = *(const ushort4*)(mskh + kt * 64 + bkb * 16 + quad * 4);
            const float mkf[4] = {bf2f(mk4.x), bf2f(mk4.y), bf2f(mk4.z), bf2f(mk4.w)};
            const int pc = ((bkb * 4 + quad) ^ psw) * 4;
            #pragma unroll
            for (int g = 0; g < 2; ++g) {
                float p0 = fmaf(__builtin_amdgcn_exp2f(st[g][0]) * mkf[0], mqf[g], fnq[g]);
                float p1 = fmaf(__builtin_amdgcn_exp2f(st[g][1]) * mkf[1], mqf[g], fnq[g]);
                float p2 = fmaf(__builtin_amdgcn_exp2f(st[g][2]) * mkf[2], mqf[g], fnq[g]);
                float p3 = fmaf(__builtin_amdgcn_exp2f(st[g][3]) * mkf[3], mqf[g], fnq[g]);
                l_i[g] += (p0 + p1) + (p2 + p3);
                ushort4 pk;
                pk.x = f2bf(p0); pk.y = f2bf(p1); pk.z = f2bf(p2); pk.w = f2bf(p3);
                *(ushort4*)(pwv + (g * 16 + l16) * 64 + pc) = pk;
            }
        }

        // ---- PV: O[g] += P[g] @ V ----
        short8 pf0[2], pf1[2];
        #pragma unroll
        for (int g = 0; g < 2; ++g) {
            pf0[g] = *(const short8*)(pwv + (g * 16 + l16) * 64 + prd0);
            pf1[g] = *(const short8*)(pwv + (g * 16 + l16) * 64 + prd1);
        }
        #pragma unroll
        for (int dhb = 0; dhb < 4; ++dhb) {
            const short8 vf0 = *(const short8*)(Vts + koff0[dhb]);
            const short8 vf1 = *(const short8*)(Vts + koff1[dhb]);
            #pragma unroll
            for (int g = 0; g < 2; ++g) {
                o[g][dhb] = __builtin_amdgcn_mfma_f32_16x16x32_bf16(pf0[g], vf0, o[g][dhb], 0, 0, 0);
                o[g][dhb] = __builtin_amdgcn_mfma_f32_16x16x32_bf16(pf1[g], vf1, o[g][dhb], 0, 0, 0);
            }
        }
    }

    // l: sum across the 4 quads holding q=l16 (lanes differ by 16/32)
    #pragma unroll
    for (int g = 0; g < 2; ++g) {
        float l = l_i[g];
        l += __shfl_xor(l, 16);
        l += __shfl_xor(l, 32);
        lw[w * 32 + g * 16 + l16] = l;  // all quads write same value
    }

    ushort_t* ob = ab + ((size_t)b * SEQ + qt * 128 + w * 32) * EMB + h * DH;
    #pragma unroll
    for (int g = 0; g < 2; ++g) {
        #pragma unroll
        for (int i = 0; i < 4; ++i) {
            const int row = g * 16 + quad * 4 + i;
            const float inv = 1.0f / lw[w * 32 + row];
            #pragma unroll
            for (int dhb = 0; dhb < 4; ++dhb)
                ob[(size_t)row * EMB + dhb * 16 + l16] = f2bf(o[g][dhb][i] * inv);
        }
    }
}

// ---------------------------------------------------------------------------
// MFMA GEMM 2: out = ab @ WoutT + bout (fp32 out).
// ---------------------------------------------------------------------------
__global__ __launch_bounds__(256) void out_mfma(const ushort_t* __restrict__ ab,
                                                const ushort_t* __restrict__ wot,
                                                const float* __restrict__ bias,
                                                float* __restrict__ out) {
    __shared__ __align__(16) ushort_t As[128 * 32];
    __shared__ __align__(16) ushort_t Bs[128 * 32];
    const int tid  = threadIdx.x;
    const int w    = tid >> 6;
    const int lane = tid & 63;
    const int l16  = lane & 15;
    const int quad = lane >> 4;
    const int wq   = w >> 1;
    const int wn   = w & 1;
    const int row0 = blockIdx.y * 128;
    const int col0 = blockIdx.x * 128;

    float4e acc[4][4];
    #pragma unroll
    for (int i = 0; i < 4; ++i)
        #pragma unroll
        for (int j = 0; j < 4; ++j) acc[i][j] = (float4e){0.f, 0.f, 0.f, 0.f};

    const int srow = tid >> 2;
    const int csrc = (tid & 3) ^ (srow & 3);

    for (int k0 = 0; k0 < EMB; k0 += 32) {
        #pragma unroll
        for (int s = 0; s < 2; ++s) {
            const int row = s * 64 + srow;
            gl_lds16(ab + (size_t)(row0 + row) * EMB + k0 + csrc * 8,
                     As + s * 2048 + w * 512);
            gl_lds16(wot + (size_t)(col0 + row) * EMB + k0 + csrc * 8,
                     Bs + s * 2048 + w * 512);
        }
        __syncthreads();
        short8 af[4], bf[4];
        #pragma unroll
        for (int mt = 0; mt < 4; ++mt) {
            const int rm = wq * 64 + mt * 16 + l16;
            af[mt] = *(const short8*)(As + rm * 32 + ((quad ^ (rm & 3)) * 8));
        }
        #pragma unroll
        for (int nt = 0; nt < 4; ++nt) {
            const int rn = wn * 64 + nt * 16 + l16;
            bf[nt] = *(const short8*)(Bs + rn * 32 + ((quad ^ (rn & 3)) * 8));
        }
        #pragma unroll
        for (int mt = 0; mt < 4; ++mt)
            #pragma unroll
            for (int nt = 0; nt < 4; ++nt)
                acc[mt][nt] = __builtin_amdgcn_mfma_f32_16x16x32_bf16(af[mt], bf[nt], acc[mt][nt], 0, 0, 0);
        __syncthreads();
    }

    #pragma unroll
    for (int nt = 0; nt < 4; ++nt) {
        const int col_g = col0 + wn * 64 + nt * 16 + l16;
        const float bz = bias[col_g];
        #pragma unroll
        for (int mt = 0; mt < 4; ++mt) {
            #pragma unroll
            for (int i = 0; i < 4; ++i) {
                const int row_g = row0 + wq * 64 + mt * 16 + quad * 4 + i;
                out[(size_t)row_g * EMB + col_g] = acc[mt][nt][i] + bz;
            }
        }
    }
}

// ---------------------------------------------------------------------------
extern "C" void kernel_launch(void* const* d_in, const int* in_sizes, int n_in,
                              void* d_out, int out_size, void* d_ws, size_t ws_size,
                              hipStream_t stream) {
    const float* x    = (const float*)d_in[0];
    const void*  mask = d_in[1];
    const float* Wqkv = (const float*)d_in[2];
    const float* bqkv = (const float*)d_in[3];
    const float* Wout = (const float*)d_in[4];
    const float* bout = (const float*)d_in[5];
    float* out = (float*)d_out;

    ushort_t* xb  = (ushort_t*)d_ws;                 // [16384][512]
    ushort_t* wqt = xb + (size_t)MROWS * EMB;        // [1536][512]
    ushort_t* wot = wqt + (size_t)1536 * EMB;        // [512][512]
    ushort_t* qb  = wot + (size_t)EMB * EMB;         // [BH][N][DH]
    ushort_t* kb  = qb + QKV_ELEMS;
    ushort_t* vt  = kb + QKV_ELEMS;                  // [BH][DH][N]
    ushort_t* ab  = vt + QKV_ELEMS;                  // [B][N][EMB]
    ushort_t* pmh = ab + (size_t)MROWS * EMB;        // bf16 [B][SEQ]

    prep<<<dim3(PREP_TOTAL), 256, 0, stream>>>(x, mask, Wqkv, Wout, xb, pmh, wqt, wot);
    qkv_mfma<<<dim3(1536 / 128, MROWS / 128), 256, 0, stream>>>(xb, wqt, bqkv, qb, kb, vt);
    attn_mfma<<<dim3(NBH * (SEQ / 128)), 256, 0, stream>>>(qb, kb, vt, pmh, ab);
    out_mfma<<<dim3(EMB / 128, MROWS / 128), 256, 0, stream>>>(ab, wot, bout, out);
}

// Round 8
// 255.286 us; speedup vs baseline: 1.1319x; 1.0969x over previous
//
#include <hip/hip_runtime.h>
#include <math.h>

#define BB  8
#define SEQ 2048
#define EMB 512
#define NH  8
#define DH  64
#define NBH (BB * NH)                      // 64
#define MROWS (BB * SEQ)                   // 16384
#define QKV_ELEMS ((size_t)NBH * SEQ * DH) // 8388608
#define MASK_ELEMS (BB * (SEQ - 1))        // 16376
// 512^-0.5 * log2(e): q pre-scaled so softmax uses exp2 directly
#define QSCALE 0.06375871307545f

typedef __attribute__((ext_vector_type(8)))  short short8;
typedef __attribute__((ext_vector_type(4)))  float float4e;
typedef __attribute__((ext_vector_type(16))) float float16e;
typedef __attribute__((ext_vector_type(4)))  unsigned int uint4e;
typedef unsigned short ushort_t;

static __device__ inline unsigned short f2bf(float f) {
    unsigned int u = __float_as_uint(f);
    unsigned int r = (u + 0x7fffu + ((u >> 16) & 1u)) >> 16;
    return (unsigned short)r;
}

static __device__ inline void gl_lds16(const unsigned short* g, unsigned short* l) {
    __builtin_amdgcn_global_load_lds(
        (const __attribute__((address_space(1))) void*)g,
        (__attribute__((address_space(3))) void*)l, 16, 0, 0);
}

// ---------------------------------------------------------------------------
// Fused prep: one launch, blockIdx-partitioned.
//   [0, 8192)        conv_x : x fp32 -> xb bf16
//   [8192, 8256)     decode_mask -> pmf f32 [B][SEQ] (1.0/0.0, CLS=1)
//   [8256, 9024)     wtrans Wqkv -> wqt bf16 [1536][512]
//   [9024, 9280)     wtrans Wout -> wot bf16 [512][512]
// ---------------------------------------------------------------------------
#define PREP_CONV   8192
#define PREP_MASK   (PREP_CONV + 64)
#define PREP_WQ     (PREP_MASK + (1536 / 32) * (EMB / 32))
#define PREP_TOTAL  (PREP_WQ + (EMB / 32) * (EMB / 32))

__global__ __launch_bounds__(256) void prep(const float* __restrict__ x,
                                            const void* __restrict__ mraw,
                                            const float* __restrict__ Wqkv,
                                            const float* __restrict__ Wout,
                                            ushort_t* __restrict__ xb,
                                            float* __restrict__ pmf,
                                            ushort_t* __restrict__ wqt,
                                            ushort_t* __restrict__ wot) {
    __shared__ float T[32][33];
    __shared__ int flag;
    const int bid = blockIdx.x;
    const int tid = threadIdx.x;

    if (bid < PREP_CONV) {
        const size_t i = ((size_t)bid * 256 + tid) * 4;
        float4 v = *(const float4*)&x[i];
        ushort4 o;
        o.x = f2bf(v.x); o.y = f2bf(v.y); o.z = f2bf(v.z); o.w = f2bf(v.w);
        *(ushort4*)&xb[i] = o;
    } else if (bid < PREP_MASK) {
        if (tid == 0) flag = 0;
        __syncthreads();
        const unsigned int* mi = (const unsigned int*)mraw;
        int local = 0;
        for (int i = tid; i < MASK_ELEMS / 4; i += 256) {
            if (mi[i] > 1u) local = 1;
        }
        if (local) flag = 1;
        __syncthreads();
        const int isbyte = flag;
        const unsigned char* mb = (const unsigned char*)mraw;
        const int* m32 = (const int*)mraw;
        const int i = (bid - PREP_CONV) * 256 + tid;
        const int b = i >> 11, n = i & (SEQ - 1);
        int v;
        if (n == 0) v = 1;
        else {
            const int src = b * (SEQ - 1) + n - 1;
            v = isbyte ? (int)mb[src] : (m32[src] != 0 ? 1 : 0);
        }
        pmf[i] = v ? 1.0f : 0.0f;
    } else {
        const float* src;
        ushort_t* dst;
        int N, idx;
        if (bid < PREP_WQ) {
            src = Wqkv; dst = wqt; N = 1536; idx = bid - PREP_MASK;
        } else {
            src = Wout; dst = wot; N = EMB; idx = bid - PREP_WQ;
        }
        const int nb = N / 32;
        const int n0 = (idx % nb) * 32;
        const int k0 = (idx / nb) * 32;
        {
            const int r = tid >> 3, c4 = (tid & 7) * 4;
            *(float4*)&T[r][c4] = *(const float4*)&src[(size_t)(k0 + r) * N + n0 + c4];
        }
        __syncthreads();
        const int n = tid >> 3, k4 = (tid & 7) * 4;
        ushort4 hv;
        hv.x = f2bf(T[k4 + 0][n]);
        hv.y = f2bf(T[k4 + 1][n]);
        hv.z = f2bf(T[k4 + 2][n]);
        hv.w = f2bf(T[k4 + 3][n]);
        *(ushort4*)&dst[(size_t)(n0 + n) * EMB + k0 + k4] = hv;
    }
}

// ---------------------------------------------------------------------------
// MFMA GEMM 1: qkv = xb @ WqkvT + bqkv.
//   q -> qb [BH][N][DH] (pre-scaled by QSCALE), k -> kb, v -> vt [BH][DH][N].
// ---------------------------------------------------------------------------
__global__ __launch_bounds__(256) void qkv_mfma(const ushort_t* __restrict__ xb,
                                                const ushort_t* __restrict__ wt,
                                                const float* __restrict__ bias,
                                                ushort_t* __restrict__ qb,
                                                ushort_t* __restrict__ kb,
                                                ushort_t* __restrict__ vt) {
    __shared__ __align__(16) ushort_t As[128 * 32];
    __shared__ __align__(16) ushort_t Bs[128 * 32];
    const int tid  = threadIdx.x;
    const int w    = tid >> 6;
    const int lane = tid & 63;
    const int l16  = lane & 15;
    const int quad = lane >> 4;
    const int wq   = w >> 1;
    const int wn   = w & 1;
    const int row0 = blockIdx.y * 128;
    const int col0 = blockIdx.x * 128;

    float4e acc[4][4];
    #pragma unroll
    for (int i = 0; i < 4; ++i)
        #pragma unroll
        for (int j = 0; j < 4; ++j) acc[i][j] = (float4e){0.f, 0.f, 0.f, 0.f};

    const int srow = tid >> 2;
    const int csrc = (tid & 3) ^ (srow & 3);

    for (int k0 = 0; k0 < EMB; k0 += 32) {
        #pragma unroll
        for (int s = 0; s < 2; ++s) {
            const int row = s * 64 + srow;
            gl_lds16(xb + (size_t)(row0 + row) * EMB + k0 + csrc * 8,
                     As + s * 2048 + w * 512);
            gl_lds16(wt + (size_t)(col0 + row) * EMB + k0 + csrc * 8,
                     Bs + s * 2048 + w * 512);
        }
        __syncthreads();
        short8 af[4], bf[4];
        #pragma unroll
        for (int mt = 0; mt < 4; ++mt) {
            const int rm = wq * 64 + mt * 16 + l16;
            af[mt] = *(const short8*)(As + rm * 32 + ((quad ^ (rm & 3)) * 8));
        }
        #pragma unroll
        for (int nt = 0; nt < 4; ++nt) {
            const int rn = wn * 64 + nt * 16 + l16;
            bf[nt] = *(const short8*)(Bs + rn * 32 + ((quad ^ (rn & 3)) * 8));
        }
        #pragma unroll
        for (int mt = 0; mt < 4; ++mt)
            #pragma unroll
            for (int nt = 0; nt < 4; ++nt)
                acc[mt][nt] = __builtin_amdgcn_mfma_f32_16x16x32_bf16(af[mt], bf[nt], acc[mt][nt], 0, 0, 0);
        __syncthreads();
    }

    #pragma unroll
    for (int nt = 0; nt < 4; ++nt) {
        const int cb    = col0 + wn * 64 + nt * 16;
        const int which = cb >> 9;
        const int h     = (cb >> 6) & 7;
        const int dcol  = (cb & 63) + l16;
        const float bz  = bias[cb + l16];
        if (which == 2) {
            #pragma unroll
            for (int mt = 0; mt < 4; ++mt) {
                const int rg = row0 + wq * 64 + mt * 16 + quad * 4;
                const int b = rg >> 11, n = rg & (SEQ - 1);
                ushort4 ov;
                ov.x = f2bf(acc[mt][nt][0] + bz);
                ov.y = f2bf(acc[mt][nt][1] + bz);
                ov.z = f2bf(acc[mt][nt][2] + bz);
                ov.w = f2bf(acc[mt][nt][3] + bz);
                *(ushort4*)&vt[((size_t)(b * NH + h) * DH + dcol) * SEQ + n] = ov;
            }
        } else {
            ushort_t* base = (which == 0) ? qb : kb;
            const float sc = (which == 0) ? QSCALE : 1.0f;
            #pragma unroll
            for (int mt = 0; mt < 4; ++mt) {
                #pragma unroll
                for (int i = 0; i < 4; ++i) {
                    const int rg = row0 + wq * 64 + mt * 16 + quad * 4 + i;
                    const int b = rg >> 11;
                    const int n = rg & (SEQ - 1);
                    base[((size_t)(b * NH + h) * SEQ + n) * DH + dcol] =
                        f2bf((acc[mt][nt][i] + bz) * sc);
                }
            }
        }
    }
}

// ---------------------------------------------------------------------------
// MFMA flash attention v6: 32x32x16 MFMA, wave owns 64 q (2 tiles of 32),
// block = 2 waves = 128 q. S computed transposed (A=K, B=Q) so C cols = q =
// lane&31; P->A-operand transform is a half-wave register exchange
// (pack bf16 pairs, one shfl_xor(32) + cndmask) — NO LDS for P.
// K/V tiles double-buffered in LDS via global_load_lds (swizzle source-folded):
// stage kt+1 before computing kt -> 1 barrier/kt, drain covered by compute.
// Masks f32 from global (broadcast loads). Fixed-max softmax:
//   p = fmaf(exp2(s)*mk, mq, 1-mq)  (exact reference -1e9 semantics).
// ---------------------------------------------------------------------------
__device__ inline void stage_tile(const ushort_t* kbh, const ushort_t* vbh, int kt,
                                  ushort_t* Kd, ushort_t* Vd,
                                  const int* crow, const int* csoff, int wbase) {
    #pragma unroll
    for (int j = 0; j < 4; ++j) {
        gl_lds16(kbh + (size_t)(kt * 64 + crow[j]) * DH + csoff[j],
                 Kd + (j * 128 + wbase) * 8);
        gl_lds16(vbh + (size_t)crow[j] * SEQ + kt * 64 + csoff[j],
                 Vd + (j * 128 + wbase) * 8);
    }
}

__global__ __launch_bounds__(128, 2) void attn_mfma(const ushort_t* __restrict__ qb,
                                                    const ushort_t* __restrict__ kb,
                                                    const ushort_t* __restrict__ vt,
                                                    const float* __restrict__ pmf,
                                                    ushort_t* __restrict__ ab) {
    __shared__ __align__(16) ushort_t Ks[2][64 * 64];   // 16KB (dbuf)
    __shared__ __align__(16) ushort_t Vts[2][64 * 64];  // 16KB (dbuf)
    __shared__ float lw[2][64];

    const int tid = threadIdx.x;
    const int w   = tid >> 6;          // 0,1
    const int lane = tid & 63;
    const int l5  = lane & 31;
    const int h   = lane >> 5;         // half-wave
    const int qt  = blockIdx.x & 15;   // 128-q tile
    const int bh  = blockIdx.x >> 4;
    const int b   = bh >> 3;
    const int hh  = bh & 7;
    const int q0  = qt * 128 + w * 64; // wave's first q row

    // Q fragments (B-operand of S^T): n=q=l5, k=dh=kc*16+h*8+j
    const ushort_t* qbh = qb + (size_t)bh * SEQ * DH;
    short8 qf[2][4];
    #pragma unroll
    for (int t = 0; t < 2; ++t)
        #pragma unroll
        for (int kc = 0; kc < 4; ++kc)
            qf[t][kc] = *(const short8*)(qbh + (size_t)(q0 + t * 32 + l5) * DH + kc * 16 + h * 8);

    // q masks (per-lane scalar per tile)
    float mq[2], fnq[2];
    #pragma unroll
    for (int t = 0; t < 2; ++t) {
        mq[t]  = pmf[b * SEQ + q0 + t * 32 + l5];
        fnq[t] = 1.0f - mq[t];
    }

    // staging chunk params: 512 chunks/tile, 128 thr -> 4 each; swizzle
    // ((c&7)^(row&7)) folded into the SOURCE column.
    int crow[4], csoff[4];
    #pragma unroll
    for (int j = 0; j < 4; ++j) {
        const int c = j * 128 + tid;
        crow[j]  = c >> 3;
        csoff[j] = ((c & 7) ^ (crow[j] & 7)) * 8;
    }
    const int wbase = w * 64;
    const ushort_t* kbh = kb + (size_t)bh * SEQ * DH;
    const ushort_t* vbh = vt + (size_t)bh * DH * SEQ;
    const float*    mrow = pmf + b * SEQ;

    float16e o[2][2];   // [t][dh-tile]
    #pragma unroll
    for (int t = 0; t < 2; ++t)
        #pragma unroll
        for (int d = 0; d < 2; ++d) o[t][d] = (float16e)0.0f;
    float l_i[2] = {0.f, 0.f};

    stage_tile(kbh, vbh, 0, Ks[0], Vts[0], crow, csoff, wbase);

    for (int kt = 0; kt < 32; ++kt) {
        __syncthreads();   // staged tile visible; drain covered by prev compute
        const int cur = kt & 1;
        if (kt < 31)
            stage_tile(kbh, vbh, kt + 1, Ks[cur ^ 1], Vts[cur ^ 1], crow, csoff, wbase);

        #pragma unroll
        for (int s = 0; s < 2; ++s) {
            // ---- S^T = K·Q per 32-key tile (A=K, B=Q) ----
            const int krow = s * 32 + l5;
            short8 kf[4];
            #pragma unroll
            for (int kc = 0; kc < 4; ++kc)
                kf[kc] = *(const short8*)(Ks[cur] + krow * 64 + (((kc * 2 + h) ^ (krow & 7)) * 8));
            float16e st[2];
            st[0] = (float16e)0.0f;
            st[1] = (float16e)0.0f;
            #pragma unroll
            for (int kc = 0; kc < 4; ++kc) {
                st[0] = __builtin_amdgcn_mfma_f32_32x32x16_bf16(kf[kc], qf[0][kc], st[0], 0, 0, 0);
                st[1] = __builtin_amdgcn_mfma_f32_32x32x16_bf16(kf[kc], qf[1][kc], st[1], 0, 0, 0);
            }

            // key masks: reg r -> key = (r&3) + 8*(r>>2) + 4h (+s*32)
            float4e mk4[4];
            #pragma unroll
            for (int g2 = 0; g2 < 4; ++g2)
                mk4[g2] = *(const float4e*)(mrow + kt * 64 + s * 32 + g2 * 8 + h * 4);

            // ---- softmax + pack + half-wave exchange -> PV A-frags ----
            short8 af[2][2];
            #pragma unroll
            for (int t = 0; t < 2; ++t) {
                unsigned int a[8];
                float lacc = 0.f;
                #pragma unroll
                for (int j = 0; j < 8; ++j) {
                    const float mk0 = mk4[j >> 1][(2 * j) & 3];
                    const float mk1 = mk4[j >> 1][(2 * j + 1) & 3];
                    const float p0 = fmaf(__builtin_amdgcn_exp2f(st[t][2 * j]) * mk0, mq[t], fnq[t]);
                    const float p1 = fmaf(__builtin_amdgcn_exp2f(st[t][2 * j + 1]) * mk1, mq[t], fnq[t]);
                    lacc += p0 + p1;
                    a[j] = (__float_as_uint(p0) >> 16) | (__float_as_uint(p1) & 0xffff0000u);
                }
                l_i[t] += lacc;
                #pragma unroll
                for (int c = 0; c < 2; ++c) {
                    const unsigned int s0 = h ? a[4 * c]     : a[4 * c + 2];
                    const unsigned int s1 = h ? a[4 * c + 1] : a[4 * c + 3];
                    const unsigned int x0 = (unsigned int)__shfl_xor((int)s0, 32);
                    const unsigned int x1 = (unsigned int)__shfl_xor((int)s1, 32);
                    uint4e fv;
                    fv.x = h ? x0 : a[4 * c];
                    fv.y = h ? x1 : a[4 * c + 1];
                    fv.z = h ? a[4 * c + 2] : x0;
                    fv.w = h ? a[4 * c + 3] : x1;
                    af[t][c] = __builtin_bit_cast(short8, fv);
                }
            }

            // ---- PV: O[t][d] += P @ V (A=P regs, B=V from LDS) ----
            #pragma unroll
            for (int c = 0; c < 2; ++c) {
                #pragma unroll
                for (int d = 0; d < 2; ++d) {
                    const int vrow = d * 32 + l5;
                    const short8 vf = *(const short8*)(Vts[cur] + vrow * 64 +
                                       (((s * 4 + c * 2 + h) ^ (vrow & 7)) * 8));
                    o[0][d] = __builtin_amdgcn_mfma_f32_32x32x16_bf16(af[0][c], vf, o[0][d], 0, 0, 0);
                    o[1][d] = __builtin_amdgcn_mfma_f32_32x32x16_bf16(af[1][c], vf, o[1][d], 0, 0, 0);
                }
            }
        }
    }

    // l: each half-wave holds its 32-key partials; combine across halves
    #pragma unroll
    for (int t = 0; t < 2; ++t) {
        const float l = l_i[t] + __shfl_xor(l_i[t], 32);
        lw[w][t * 32 + l5] = l;   // both halves write same value
    }

    ushort_t* ob = ab + ((size_t)b * SEQ + q0) * EMB + hh * DH;
    #pragma unroll
    for (int t = 0; t < 2; ++t) {
        #pragma unroll
        for (int r = 0; r < 16; ++r) {
            const int ql = (r & 3) + 8 * (r >> 2) + 4 * h;
            const float inv = 1.0f / lw[w][t * 32 + ql];
            #pragma unroll
            for (int d = 0; d < 2; ++d)
                ob[(size_t)(t * 32 + ql) * EMB + d * 32 + l5] = f2bf(o[t][d][r] * inv);
        }
    }
}

// ---------------------------------------------------------------------------
// MFMA GEMM 2: out = ab @ WoutT + bout (fp32 out).
// ---------------------------------------------------------------------------
__global__ __launch_bounds__(256) void out_mfma(const ushort_t* __restrict__ ab,
                                                const ushort_t* __restrict__ wot,
                                                const float* __restrict__ bias,
                                                float* __restrict__ out) {
    __shared__ __align__(16) ushort_t As[128 * 32];
    __shared__ __align__(16) ushort_t Bs[128 * 32];
    const int tid  = threadIdx.x;
    const int w    = tid >> 6;
    const int lane = tid & 63;
    const int l16  = lane & 15;
    const int quad = lane >> 4;
    const int wq   = w >> 1;
    const int wn   = w & 1;
    const int row0 = blockIdx.y * 128;
    const int col0 = blockIdx.x * 128;

    float4e acc[4][4];
    #pragma unroll
    for (int i = 0; i < 4; ++i)
        #pragma unroll
        for (int j = 0; j < 4; ++j) acc[i][j] = (float4e){0.f, 0.f, 0.f, 0.f};

    const int srow = tid >> 2;
    const int csrc = (tid & 3) ^ (srow & 3);

    for (int k0 = 0; k0 < EMB; k0 += 32) {
        #pragma unroll
        for (int s = 0; s < 2; ++s) {
            const int row = s * 64 + srow;
            gl_lds16(ab + (size_t)(row0 + row) * EMB + k0 + csrc * 8,
                     As + s * 2048 + w * 512);
            gl_lds16(wot + (size_t)(col0 + row) * EMB + k0 + csrc * 8,
                     Bs + s * 2048 + w * 512);
        }
        __syncthreads();
        short8 af[4], bf[4];
        #pragma unroll
        for (int mt = 0; mt < 4; ++mt) {
            const int rm = wq * 64 + mt * 16 + l16;
            af[mt] = *(const short8*)(As + rm * 32 + ((quad ^ (rm & 3)) * 8));
        }
        #pragma unroll
        for (int nt = 0; nt < 4; ++nt) {
            const int rn = wn * 64 + nt * 16 + l16;
            bf[nt] = *(const short8*)(Bs + rn * 32 + ((quad ^ (rn & 3)) * 8));
        }
        #pragma unroll
        for (int mt = 0; mt < 4; ++mt)
            #pragma unroll
            for (int nt = 0; nt < 4; ++nt)
                acc[mt][nt] = __builtin_amdgcn_mfma_f32_16x16x32_bf16(af[mt], bf[nt], acc[mt][nt], 0, 0, 0);
        __syncthreads();
    }

    #pragma unroll
    for (int nt = 0; nt < 4; ++nt) {
        const int col_g = col0 + wn * 64 + nt * 16 + l16;
        const float bz = bias[col_g];
        #pragma unroll
        for (int mt = 0; mt < 4; ++mt) {
            #pragma unroll
            for (int i = 0; i < 4; ++i) {
                const int row_g = row0 + wq * 64 + mt * 16 + quad * 4 + i;
                out[(size_t)row_g * EMB + col_g] = acc[mt][nt][i] + bz;
            }
        }
    }
}

// ---------------------------------------------------------------------------
extern "C" void kernel_launch(void* const* d_in, const int* in_sizes, int n_in,
                              void* d_out, int out_size, void* d_ws, size_t ws_size,
                              hipStream_t stream) {
    const float* x    = (const float*)d_in[0];
    const void*  mask = d_in[1];
    const float* Wqkv = (const float*)d_in[2];
    const float* bqkv = (const float*)d_in[3];
    const float* Wout = (const float*)d_in[4];
    const float* bout = (const float*)d_in[5];
    float* out = (float*)d_out;

    ushort_t* xb  = (ushort_t*)d_ws;                 // [16384][512]
    ushort_t* wqt = xb + (size_t)MROWS * EMB;        // [1536][512]
    ushort_t* wot = wqt + (size_t)1536 * EMB;        // [512][512]
    ushort_t* qb  = wot + (size_t)EMB * EMB;         // [BH][N][DH]
    ushort_t* kb  = qb + QKV_ELEMS;
    ushort_t* vt  = kb + QKV_ELEMS;                  // [BH][DH][N]
    ushort_t* ab  = vt + QKV_ELEMS;                  // [B][N][EMB]
    float*    pmf = (float*)(ab + (size_t)MROWS * EMB); // f32 [B][SEQ]

    prep<<<dim3(PREP_TOTAL), 256, 0, stream>>>(x, mask, Wqkv, Wout, xb, pmf, wqt, wot);
    qkv_mfma<<<dim3(1536 / 128, MROWS / 128), 256, 0, stream>>>(xb, wqt, bqkv, qb, kb, vt);
    attn_mfma<<<dim3(NBH * (SEQ / 128)), 128, 0, stream>>>(qb, kb, vt, pmf, ab);
    out_mfma<<<dim3(EMB / 128, MROWS / 128), 256, 0, stream>>>(ab, wot, bout, out);
}